// Round 38
// baseline (127.421 us; speedup 1.0000x reference)
//
#include <hip/hip_runtime.h>

#define B_    32
#define N_    256
#define H_    6
#define HD_   32
#define C_    192
#define C4_   768
#define TKIN  64
#define TKOUT 32
#define WULP  32u   // fast-path safety window (ulps on a32)

// ---------------------------------------------------------------------------
// Kernel A (R36-PASS + staged V): block = 512 threads = 8 waves = one (b,h)
// quarter (64 rows, 8 rows/wave). K AND V slices [256][32] staged coalesced
// into LDS (pad 33); k-gather AND PV v-reads become LDS ops. ~80KB LDS ->
// 2 blocks/CU (50% wave cap >= achieved 28%, no occupancy harm).
// Per-row arithmetic/rank/comparator byte-identical to R36-PASS.
// XCD window clustering kept (96 blocks/XCD = 4 windows).
// ---------------------------------------------------------------------------
__global__ __launch_bounds__(512) void attn_topk_kernel(
    const float* __restrict__ qkvp,
    const float* __restrict__ pfa_values,
    const int*   __restrict__ pfa_index,
    const int*   __restrict__ rpi,
    const float* __restrict__ rpb_table,
    float* __restrict__ x_pre,
    float* __restrict__ out_topv,
    float* __restrict__ out_nidx)
{
    const int lane  = threadIdx.x & 63;
    const int wslot = threadIdx.x >> 6;       // 0..7
    const int tid   = threadIdx.x;

    // ---- XCD-aware swizzle: 96 blocks/XCD = 4 windows x 6 heads x 4 quarters
    const int n  = blockIdx.x;            // 0..767
    const int x  = n & 7;                 // XCD
    const int r  = n >> 3;                // 0..95
    const int b  = x * 4 + r / 24;        // window
    const int rr = r % 24;
    const int h  = rr >> 2;               // head
    const int quarter = rr & 3;           // 64-row quarter

    __shared__ float  Kl[256][33];        // staged K-slice (pad 33)
    __shared__ float  Vl[256][33];        // staged V-slice (pad 33)
    __shared__ __align__(16) uint2 s_pk[8][64];
    __shared__ float  s_k32x[8][64];
    __shared__ double s_k64[8][64];
    __shared__ uint2  s_ai[8][TKOUT];

    // ---- stage K and V [256][32] for (b,h), coalesced ----
    {
        #pragma unroll
        for (int c = 0; c < 4; ++c) {
            const int elem = c * 512 + tid;       // 0..2047
            const int krow = elem >> 3;           // 0..255
            const int kcol = (elem & 7) * 4;      // 0,4,..,28
            const float4 kv = *(const float4*)(
                qkvp + (size_t)(b * N_ + krow) * C4_ + C_ + h * HD_ + kcol);
            Kl[krow][kcol + 0] = kv.x;
            Kl[krow][kcol + 1] = kv.y;
            Kl[krow][kcol + 2] = kv.z;
            Kl[krow][kcol + 3] = kv.w;
            const float4 vv = *(const float4*)(
                qkvp + (size_t)(b * N_ + krow) * C4_ + 2 * C_ + h * HD_ + kcol);
            Vl[krow][kcol + 0] = vv.x;
            Vl[krow][kcol + 1] = vv.y;
            Vl[krow][kcol + 2] = vv.z;
            Vl[krow][kcol + 3] = vv.w;
        }
    }
    __syncthreads();

    // ---- per-wave row loop: 8 rows each ----
    for (int it = 0; it < 8; ++it) {
        const int i   = quarter * 64 + it * 8 + wslot;   // token in window
        const int row = (b * H_ + h) * N_ + i;

        const int row_off = row * TKIN;
        const int idx  = pfa_index[row_off + lane];
        const float pv = pfa_values[row_off + lane];

        const float* qp = qkvp + (size_t)(b * N_ + i) * C4_ + h * HD_;
        const float bias = rpb_table[rpi[i * N_ + idx] * H_ + h];
        const float* kl = &Kl[idx][0];

        // ---- f32 chain: sequential no-FMA dot, k from LDS (bit-exact) ----
        float acc;
        {
            #pragma clang fp contract(off)
            const float SC = 0.17677669529663687f;
            acc = 0.f;
            for (int d = 0; d < HD_; ++d) {
                const float qd   = qp[d] * SC;
                const float prod = qd * kl[d];
                acc = acc + prod;
            }
            acc = acc + bias;
        }

        // ---- f32 row max ----
        float m = acc;
        #pragma unroll
        for (int s = 32; s; s >>= 1) m = fmaxf(m, __shfl_xor(m, s));

        // ---- e = exp(acc - m), CR f32 via double ----
        float e;
        {
            #pragma clang fp contract(off)
            const float t = acc - m;
            e = (float)exp((double)t);
        }

        // ---- ssum: pairwise-8 via shuffles ----
        float ssum;
        {
            #pragma clang fp contract(off)
            float y = e, r2 = e;
            #pragma unroll
            for (int k = 1; k < 8; ++k) { y = __shfl_down(y, 8); r2 = r2 + y; }
            const float t1 = r2 + __shfl_xor(r2, 1);
            const float t2 = t1 + __shfl_xor(t1, 2);
            const float t3 = t2 + __shfl_xor(t2, 4);
            ssum = __shfl(t3, 0);
        }

        // ---- w = (e/ssum)*pv ----
        float w;
        {
            #pragma clang fp contract(off)
            const float s32 = e / ssum;
            w = s32 * pv;
        }

        // ---- denom ----
        float denom;
        {
            #pragma clang fp contract(off)
            float y = w, r2 = w;
            #pragma unroll
            for (int k = 1; k < 8; ++k) { y = __shfl_down(y, 8); r2 = r2 + y; }
            const float t1 = r2 + __shfl_xor(r2, 1);
            const float t2 = t1 + __shfl_xor(t1, 2);
            const float t3 = t2 + __shfl_xor(t2, 4);
            denom = __shfl(t3, 0);
        }

        // ---- a32 ----
        float a32;
        {
            #pragma clang fp contract(off)
            a32 = (w + 1e-20f) / (denom + 1e-20f);
        }

        // ---- packed key ----
        const unsigned abits = __float_as_uint(a32);
        const unsigned long long myK =
            ((unsigned long long)abits << 6) | (unsigned long long)(63 - lane);
        s_pk[wslot][lane] = make_uint2((unsigned)myK, (unsigned)(myK >> 32));

        // ---- rank: two keys per ds_read_b128 ----
        int rank = 0;
        #pragma unroll
        for (int j2 = 0; j2 < 32; ++j2) {
            const uint4 kk = *(const uint4*)&s_pk[wslot][j2 * 2];
            const unsigned long long K0 =
                ((unsigned long long)kk.y << 32) | (unsigned long long)kk.x;
            const unsigned long long K1 =
                ((unsigned long long)kk.w << 32) | (unsigned long long)kk.z;
            rank += (K0 > myK);
            rank += (K1 > myK);
        }

        // ---- near detect: sorted adjacency ----
        {
            const int sorted = __builtin_amdgcn_ds_permute(rank << 2, (int)abits);
            const int nxt    = __shfl_down(sorted, 1);
            const unsigned gap = (unsigned)sorted - (unsigned)nxt;
            const bool nearf = (lane < 63) && (gap <= WULP);
            if (__any(nearf)) {
                // slow path (rare): okey comparator (R20/R36 verbatim)
                double acc64 = 0.0;
                for (int d = 0; d < HD_; ++d)
                    acc64 = fma((double)qp[d], (double)kl[d], acc64);
                acc64 = acc64 * 0.17677669529663687 + (double)bias;
                const double okey = exp(acc64) * (double)pv;
                s_k64[wslot][lane] = okey;
                s_k32x[wslot][lane] = a32;

                rank = 0;
                #pragma unroll
                for (int j = 0; j < 64; ++j) {
                    const float  kj32 = s_k32x[wslot][j];
                    const double kj64 = s_k64[wslot][j];
                    const bool tie  = (kj32 == a32);
                    const bool lt64 = (kj64 < okey);
                    const bool gt64 = (kj64 > okey);
                    const bool eq64 = (kj64 == okey);
                    const bool before = tie ? (lt64 || (eq64 && j < lane))
                                            : (gt64 || (eq64 && kj32 > a32));
                    rank += before;
                }
            }
        }

        if (rank < TKOUT) {
            const size_t obase = (size_t)row * TKOUT + rank;
            out_topv[obase] = a32;
            out_nidx[obase] = (float)idx;
            s_ai[wslot][rank] = make_uint2(abits, (unsigned)idx);
        }

        // ---- PV (v from LDS: pad-33 spreads banks; 2-way across halves) ----
        const int d    = lane & 31;
        const int half = lane >> 5;
        float xd = 0.f;
        #pragma unroll
        for (int s16 = 0; s16 < 16; ++s16) {
            const int sI = half * 16 + s16;
            const uint2 ai = s_ai[wslot][sI];
            const float av = __uint_as_float(ai.x);
            const int   vi = (int)ai.y;
            xd += av * Vl[vi][d];
        }
        xd += __shfl_xor(xd, 32);
        if (half == 0) {
            const float lepe = qkvp[(size_t)(b * N_ + i) * C4_ + 3 * C_ + h * HD_ + d];
            x_pre[(size_t)(b * N_ + i) * C_ + h * HD_ + d] = xd + lepe;
        }
    }
}

// ---------------------------------------------------------------------------
#define TB_ 8
__global__ __launch_bounds__(192) void proj_kernel(
    const float* __restrict__ x_pre,
    const float* __restrict__ w,
    const float* __restrict__ bias,
    float* __restrict__ out)
{
    __shared__ float xs[TB_ * C_];
    const int o    = threadIdx.x;
    const int tok0 = blockIdx.x * TB_;

    #pragma unroll
    for (int r = 0; r < TB_; ++r)
        xs[r * C_ + o] = x_pre[(size_t)(tok0 + r) * C_ + o];
    __syncthreads();

    float accv[TB_];
    #pragma unroll
    for (int t = 0; t < TB_; ++t) accv[t] = 0.f;

    const float* wrow = w + (size_t)o * C_;
    for (int c = 0; c < C_; c += 4) {
        const float4 wv = *(const float4*)(wrow + c);
        #pragma unroll
        for (int t = 0; t < TB_; ++t) {
            const float4 xv = *(const float4*)(&xs[t * C_ + c]);
            accv[t] += xv.x * wv.x + xv.y * wv.y + xv.z * wv.z + xv.w * wv.w;
        }
    }
    const float bo = bias[o];
    #pragma unroll
    for (int t = 0; t < TB_; ++t)
        out[(size_t)(tok0 + t) * C_ + o] = accv[t] + bo;
}

// ---------------------------------------------------------------------------
extern "C" void kernel_launch(void* const* d_in, const int* in_sizes, int n_in,
                              void* d_out, int out_size, void* d_ws, size_t ws_size,
                              hipStream_t stream) {
    const float* qkvp       = (const float*)d_in[0];
    const float* pfa_values = (const float*)d_in[1];
    const int*   pfa_index  = (const int*)d_in[2];
    const int*   rpi        = (const int*)d_in[3];
    const float* rpb_table  = (const float*)d_in[4];
    const float* proj_w     = (const float*)d_in[5];
    const float* proj_b     = (const float*)d_in[6];

    float* out = (float*)d_out;
    float* out_x    = out;
    float* out_topv = out + (size_t)B_ * N_ * C_;
    float* out_nidx = out_topv + (size_t)B_ * H_ * N_ * TKOUT;

    float* x_pre = (float*)d_ws;

    attn_topk_kernel<<<768, 512, 0, stream>>>(
        qkvp, pfa_values, pfa_index, rpi, rpb_table, x_pre, out_topv, out_nidx);

    const int ntok = B_ * N_;                            // 8192
    proj_kernel<<<ntok / TB_, 192, 0, stream>>>(x_pre, proj_w, proj_b, out_x);
}

// Round 39
// 110.738 us; speedup vs baseline: 1.1507x; 1.1507x over previous
//
#include <hip/hip_runtime.h>

#define B_    32
#define N_    256
#define H_    6
#define HD_   32
#define C_    192
#define C4_   768
#define TKIN  64
#define TKOUT 32
#define WULP  32u   // fast-path safety window (ulps on a32)

// ---------------------------------------------------------------------------
// FINAL (R36-PASS verbatim): block = 512 threads = 8 waves = one (b,h)
// quarter (64 rows, 8 rows/wave). K-slice [256][32] staged coalesced into
// LDS (pad 33); k-gathers become LDS reads (TA-transaction elimination —
// the validated lever). Per-row: canonical numpy-f32 chain (bit-exact) ->
// a32; u64 packed-key rank; 32-ulp sorted-adjacency near detect; rare rows
// run the R20-validated f64 okey comparator. XCD window clustering for L2.
// ---------------------------------------------------------------------------
__global__ __launch_bounds__(512) void attn_topk_kernel(
    const float* __restrict__ qkvp,
    const float* __restrict__ pfa_values,
    const int*   __restrict__ pfa_index,
    const int*   __restrict__ rpi,
    const float* __restrict__ rpb_table,
    float* __restrict__ x_pre,
    float* __restrict__ out_topv,
    float* __restrict__ out_nidx)
{
    const int lane  = threadIdx.x & 63;
    const int wslot = threadIdx.x >> 6;       // 0..7
    const int tid   = threadIdx.x;

    // ---- XCD-aware swizzle: 96 blocks/XCD = 4 windows x 6 heads x 4 quarters
    const int n  = blockIdx.x;            // 0..767
    const int x  = n & 7;                 // XCD
    const int r  = n >> 3;                // 0..95
    const int b  = x * 4 + r / 24;        // window
    const int rr = r % 24;
    const int h  = rr >> 2;               // head
    const int quarter = rr & 3;           // 64-row quarter

    __shared__ float  Kl[256][33];        // staged K-slice (pad 33)
    __shared__ __align__(16) uint2 s_pk[8][64];
    __shared__ float  s_k32x[8][64];
    __shared__ double s_k64[8][64];
    __shared__ uint2  s_ai[8][TKOUT];

    // ---- stage K[256][32] for (b,h), coalesced: 4 float4 per thread ----
    {
        #pragma unroll
        for (int c = 0; c < 4; ++c) {
            const int elem = c * 512 + tid;       // 0..2047
            const int krow = elem >> 3;           // 0..255
            const int kcol = (elem & 7) * 4;      // 0,4,..,28
            const float4 v = *(const float4*)(
                qkvp + (size_t)(b * N_ + krow) * C4_ + C_ + h * HD_ + kcol);
            Kl[krow][kcol + 0] = v.x;
            Kl[krow][kcol + 1] = v.y;
            Kl[krow][kcol + 2] = v.z;
            Kl[krow][kcol + 3] = v.w;
        }
    }
    __syncthreads();

    // ---- per-wave row loop: 8 rows each ----
    for (int it = 0; it < 8; ++it) {
        const int i   = quarter * 64 + it * 8 + wslot;   // token in window
        const int row = (b * H_ + h) * N_ + i;

        const int row_off = row * TKIN;
        const int idx  = pfa_index[row_off + lane];
        const float pv = pfa_values[row_off + lane];

        const float* qp = qkvp + (size_t)(b * N_ + i) * C4_ + h * HD_;
        const float bias = rpb_table[rpi[i * N_ + idx] * H_ + h];
        const float* kl = &Kl[idx][0];

        // ---- f32 chain: sequential no-FMA dot, k from LDS (bit-exact) ----
        float acc;
        {
            #pragma clang fp contract(off)
            const float SC = 0.17677669529663687f;
            acc = 0.f;
            for (int d = 0; d < HD_; ++d) {
                const float qd   = qp[d] * SC;
                const float prod = qd * kl[d];
                acc = acc + prod;
            }
            acc = acc + bias;
        }

        // ---- f32 row max ----
        float m = acc;
        #pragma unroll
        for (int s = 32; s; s >>= 1) m = fmaxf(m, __shfl_xor(m, s));

        // ---- e = exp(acc - m), CR f32 via double ----
        float e;
        {
            #pragma clang fp contract(off)
            const float t = acc - m;
            e = (float)exp((double)t);
        }

        // ---- ssum: pairwise-8 via shuffles ----
        float ssum;
        {
            #pragma clang fp contract(off)
            float y = e, r2 = e;
            #pragma unroll
            for (int k = 1; k < 8; ++k) { y = __shfl_down(y, 8); r2 = r2 + y; }
            const float t1 = r2 + __shfl_xor(r2, 1);
            const float t2 = t1 + __shfl_xor(t1, 2);
            const float t3 = t2 + __shfl_xor(t2, 4);
            ssum = __shfl(t3, 0);
        }

        // ---- w = (e/ssum)*pv ----
        float w;
        {
            #pragma clang fp contract(off)
            const float s32 = e / ssum;
            w = s32 * pv;
        }

        // ---- denom ----
        float denom;
        {
            #pragma clang fp contract(off)
            float y = w, r2 = w;
            #pragma unroll
            for (int k = 1; k < 8; ++k) { y = __shfl_down(y, 8); r2 = r2 + y; }
            const float t1 = r2 + __shfl_xor(r2, 1);
            const float t2 = t1 + __shfl_xor(t1, 2);
            const float t3 = t2 + __shfl_xor(t2, 4);
            denom = __shfl(t3, 0);
        }

        // ---- a32 ----
        float a32;
        {
            #pragma clang fp contract(off)
            a32 = (w + 1e-20f) / (denom + 1e-20f);
        }

        // ---- packed key ----
        const unsigned abits = __float_as_uint(a32);
        const unsigned long long myK =
            ((unsigned long long)abits << 6) | (unsigned long long)(63 - lane);
        s_pk[wslot][lane] = make_uint2((unsigned)myK, (unsigned)(myK >> 32));

        // ---- rank: two keys per ds_read_b128 ----
        int rank = 0;
        #pragma unroll
        for (int j2 = 0; j2 < 32; ++j2) {
            const uint4 kk = *(const uint4*)&s_pk[wslot][j2 * 2];
            const unsigned long long K0 =
                ((unsigned long long)kk.y << 32) | (unsigned long long)kk.x;
            const unsigned long long K1 =
                ((unsigned long long)kk.w << 32) | (unsigned long long)kk.z;
            rank += (K0 > myK);
            rank += (K1 > myK);
        }

        // ---- near detect: sorted adjacency ----
        {
            const int sorted = __builtin_amdgcn_ds_permute(rank << 2, (int)abits);
            const int nxt    = __shfl_down(sorted, 1);
            const unsigned gap = (unsigned)sorted - (unsigned)nxt;
            const bool nearf = (lane < 63) && (gap <= WULP);
            if (__any(nearf)) {
                // slow path (rare): okey comparator (R20/R36 verbatim)
                double acc64 = 0.0;
                for (int d = 0; d < HD_; ++d)
                    acc64 = fma((double)qp[d], (double)kl[d], acc64);
                acc64 = acc64 * 0.17677669529663687 + (double)bias;
                const double okey = exp(acc64) * (double)pv;
                s_k64[wslot][lane] = okey;
                s_k32x[wslot][lane] = a32;

                rank = 0;
                #pragma unroll
                for (int j = 0; j < 64; ++j) {
                    const float  kj32 = s_k32x[wslot][j];
                    const double kj64 = s_k64[wslot][j];
                    const bool tie  = (kj32 == a32);
                    const bool lt64 = (kj64 < okey);
                    const bool gt64 = (kj64 > okey);
                    const bool eq64 = (kj64 == okey);
                    const bool before = tie ? (lt64 || (eq64 && j < lane))
                                            : (gt64 || (eq64 && kj32 > a32));
                    rank += before;
                }
            }
        }

        if (rank < TKOUT) {
            const size_t obase = (size_t)row * TKOUT + rank;
            out_topv[obase] = a32;
            out_nidx[obase] = (float)idx;
            s_ai[wslot][rank] = make_uint2(abits, (unsigned)idx);
        }

        // ---- PV (v from global: coalesced per half-wave, L2-clustered) ----
        const int d    = lane & 31;
        const int half = lane >> 5;
        float xd = 0.f;
        #pragma unroll
        for (int s16 = 0; s16 < 16; ++s16) {
            const int sI = half * 16 + s16;
            const uint2 ai = s_ai[wslot][sI];
            const float av = __uint_as_float(ai.x);
            const int   vi = (int)ai.y;
            xd += av * qkvp[(size_t)(b * N_ + vi) * C4_ + 2 * C_ + h * HD_ + d];
        }
        xd += __shfl_xor(xd, 32);
        if (half == 0) {
            const float lepe = qkvp[(size_t)(b * N_ + i) * C4_ + 3 * C_ + h * HD_ + d];
            x_pre[(size_t)(b * N_ + i) * C_ + h * HD_ + d] = xd + lepe;
        }
    }
}

// ---------------------------------------------------------------------------
#define TB_ 8
__global__ __launch_bounds__(192) void proj_kernel(
    const float* __restrict__ x_pre,
    const float* __restrict__ w,
    const float* __restrict__ bias,
    float* __restrict__ out)
{
    __shared__ float xs[TB_ * C_];
    const int o    = threadIdx.x;
    const int tok0 = blockIdx.x * TB_;

    #pragma unroll
    for (int r = 0; r < TB_; ++r)
        xs[r * C_ + o] = x_pre[(size_t)(tok0 + r) * C_ + o];
    __syncthreads();

    float accv[TB_];
    #pragma unroll
    for (int t = 0; t < TB_; ++t) accv[t] = 0.f;

    const float* wrow = w + (size_t)o * C_;
    for (int c = 0; c < C_; c += 4) {
        const float4 wv = *(const float4*)(wrow + c);
        #pragma unroll
        for (int t = 0; t < TB_; ++t) {
            const float4 xv = *(const float4*)(&xs[t * C_ + c]);
            accv[t] += xv.x * wv.x + xv.y * wv.y + xv.z * wv.z + xv.w * wv.w;
        }
    }
    const float bo = bias[o];
    #pragma unroll
    for (int t = 0; t < TB_; ++t)
        out[(size_t)(tok0 + t) * C_ + o] = accv[t] + bo;
}

// ---------------------------------------------------------------------------
extern "C" void kernel_launch(void* const* d_in, const int* in_sizes, int n_in,
                              void* d_out, int out_size, void* d_ws, size_t ws_size,
                              hipStream_t stream) {
    const float* qkvp       = (const float*)d_in[0];
    const float* pfa_values = (const float*)d_in[1];
    const int*   pfa_index  = (const int*)d_in[2];
    const int*   rpi        = (const int*)d_in[3];
    const float* rpb_table  = (const float*)d_in[4];
    const float* proj_w     = (const float*)d_in[5];
    const float* proj_b     = (const float*)d_in[6];

    float* out = (float*)d_out;
    float* out_x    = out;
    float* out_topv = out + (size_t)B_ * N_ * C_;
    float* out_nidx = out_topv + (size_t)B_ * H_ * N_ * TKOUT;

    float* x_pre = (float*)d_ws;

    attn_topk_kernel<<<768, 512, 0, stream>>>(
        qkvp, pfa_values, pfa_index, rpi, rpb_table, x_pre, out_topv, out_nidx);

    const int ntok = B_ * N_;                            // 8192
    proj_kernel<<<ntok / TB_, 192, 0, stream>>>(x_pre, proj_w, proj_b, out_x);
}

// Round 40
// 108.162 us; speedup vs baseline: 1.1781x; 1.0238x over previous
//
#include <hip/hip_runtime.h>

#define B_    32
#define N_    256
#define H_    6
#define HD_   32
#define C_    192
#define C4_   768
#define TKIN  64
#define TKOUT 32
#define WULP  32u   // fast-path safety window (ulps on a32)

// ---------------------------------------------------------------------------
// Kernel A (R36/R39-PASS verbatim): block = 512 threads = 8 waves = one (b,h)
// quarter (64 rows, 8 rows/wave). K-slice staged in LDS (TA-transaction
// elimination). Canonical numpy-f32 chain; u64 packed rank; 32-ulp near
// detect; rare R20 okey comparator. XCD window clustering.
// ---------------------------------------------------------------------------
__global__ __launch_bounds__(512) void attn_topk_kernel(
    const float* __restrict__ qkvp,
    const float* __restrict__ pfa_values,
    const int*   __restrict__ pfa_index,
    const int*   __restrict__ rpi,
    const float* __restrict__ rpb_table,
    float* __restrict__ x_pre,
    float* __restrict__ out_topv,
    float* __restrict__ out_nidx)
{
    const int lane  = threadIdx.x & 63;
    const int wslot = threadIdx.x >> 6;       // 0..7
    const int tid   = threadIdx.x;

    // ---- XCD-aware swizzle: 96 blocks/XCD = 4 windows x 6 heads x 4 quarters
    const int n  = blockIdx.x;            // 0..767
    const int x  = n & 7;                 // XCD
    const int r  = n >> 3;                // 0..95
    const int b  = x * 4 + r / 24;        // window
    const int rr = r % 24;
    const int h  = rr >> 2;               // head
    const int quarter = rr & 3;           // 64-row quarter

    __shared__ float  Kl[256][33];        // staged K-slice (pad 33)
    __shared__ __align__(16) uint2 s_pk[8][64];
    __shared__ float  s_k32x[8][64];
    __shared__ double s_k64[8][64];
    __shared__ uint2  s_ai[8][TKOUT];

    // ---- stage K[256][32] for (b,h), coalesced: 4 float4 per thread ----
    {
        #pragma unroll
        for (int c = 0; c < 4; ++c) {
            const int elem = c * 512 + tid;       // 0..2047
            const int krow = elem >> 3;           // 0..255
            const int kcol = (elem & 7) * 4;      // 0,4,..,28
            const float4 v = *(const float4*)(
                qkvp + (size_t)(b * N_ + krow) * C4_ + C_ + h * HD_ + kcol);
            Kl[krow][kcol + 0] = v.x;
            Kl[krow][kcol + 1] = v.y;
            Kl[krow][kcol + 2] = v.z;
            Kl[krow][kcol + 3] = v.w;
        }
    }
    __syncthreads();

    // ---- per-wave row loop: 8 rows each ----
    for (int it = 0; it < 8; ++it) {
        const int i   = quarter * 64 + it * 8 + wslot;   // token in window
        const int row = (b * H_ + h) * N_ + i;

        const int row_off = row * TKIN;
        const int idx  = pfa_index[row_off + lane];
        const float pv = pfa_values[row_off + lane];

        const float* qp = qkvp + (size_t)(b * N_ + i) * C4_ + h * HD_;
        const float bias = rpb_table[rpi[i * N_ + idx] * H_ + h];
        const float* kl = &Kl[idx][0];

        // ---- f32 chain: sequential no-FMA dot, k from LDS (bit-exact) ----
        float acc;
        {
            #pragma clang fp contract(off)
            const float SC = 0.17677669529663687f;
            acc = 0.f;
            for (int d = 0; d < HD_; ++d) {
                const float qd   = qp[d] * SC;
                const float prod = qd * kl[d];
                acc = acc + prod;
            }
            acc = acc + bias;
        }

        // ---- f32 row max ----
        float m = acc;
        #pragma unroll
        for (int s = 32; s; s >>= 1) m = fmaxf(m, __shfl_xor(m, s));

        // ---- e = exp(acc - m), CR f32 via double ----
        float e;
        {
            #pragma clang fp contract(off)
            const float t = acc - m;
            e = (float)exp((double)t);
        }

        // ---- ssum: pairwise-8 via shuffles ----
        float ssum;
        {
            #pragma clang fp contract(off)
            float y = e, r2 = e;
            #pragma unroll
            for (int k = 1; k < 8; ++k) { y = __shfl_down(y, 8); r2 = r2 + y; }
            const float t1 = r2 + __shfl_xor(r2, 1);
            const float t2 = t1 + __shfl_xor(t1, 2);
            const float t3 = t2 + __shfl_xor(t2, 4);
            ssum = __shfl(t3, 0);
        }

        // ---- w = (e/ssum)*pv ----
        float w;
        {
            #pragma clang fp contract(off)
            const float s32 = e / ssum;
            w = s32 * pv;
        }

        // ---- denom ----
        float denom;
        {
            #pragma clang fp contract(off)
            float y = w, r2 = w;
            #pragma unroll
            for (int k = 1; k < 8; ++k) { y = __shfl_down(y, 8); r2 = r2 + y; }
            const float t1 = r2 + __shfl_xor(r2, 1);
            const float t2 = t1 + __shfl_xor(t1, 2);
            const float t3 = t2 + __shfl_xor(t2, 4);
            denom = __shfl(t3, 0);
        }

        // ---- a32 ----
        float a32;
        {
            #pragma clang fp contract(off)
            a32 = (w + 1e-20f) / (denom + 1e-20f);
        }

        // ---- packed key ----
        const unsigned abits = __float_as_uint(a32);
        const unsigned long long myK =
            ((unsigned long long)abits << 6) | (unsigned long long)(63 - lane);
        s_pk[wslot][lane] = make_uint2((unsigned)myK, (unsigned)(myK >> 32));

        // ---- rank: two keys per ds_read_b128 ----
        int rank = 0;
        #pragma unroll
        for (int j2 = 0; j2 < 32; ++j2) {
            const uint4 kk = *(const uint4*)&s_pk[wslot][j2 * 2];
            const unsigned long long K0 =
                ((unsigned long long)kk.y << 32) | (unsigned long long)kk.x;
            const unsigned long long K1 =
                ((unsigned long long)kk.w << 32) | (unsigned long long)kk.z;
            rank += (K0 > myK);
            rank += (K1 > myK);
        }

        // ---- near detect: sorted adjacency ----
        {
            const int sorted = __builtin_amdgcn_ds_permute(rank << 2, (int)abits);
            const int nxt    = __shfl_down(sorted, 1);
            const unsigned gap = (unsigned)sorted - (unsigned)nxt;
            const bool nearf = (lane < 63) && (gap <= WULP);
            if (__any(nearf)) {
                // slow path (rare): okey comparator (R20/R36 verbatim)
                double acc64 = 0.0;
                for (int d = 0; d < HD_; ++d)
                    acc64 = fma((double)qp[d], (double)kl[d], acc64);
                acc64 = acc64 * 0.17677669529663687 + (double)bias;
                const double okey = exp(acc64) * (double)pv;
                s_k64[wslot][lane] = okey;
                s_k32x[wslot][lane] = a32;

                rank = 0;
                #pragma unroll
                for (int j = 0; j < 64; ++j) {
                    const float  kj32 = s_k32x[wslot][j];
                    const double kj64 = s_k64[wslot][j];
                    const bool tie  = (kj32 == a32);
                    const bool lt64 = (kj64 < okey);
                    const bool gt64 = (kj64 > okey);
                    const bool eq64 = (kj64 == okey);
                    const bool before = tie ? (lt64 || (eq64 && j < lane))
                                            : (gt64 || (eq64 && kj32 > a32));
                    rank += before;
                }
            }
        }

        if (rank < TKOUT) {
            const size_t obase = (size_t)row * TKOUT + rank;
            out_topv[obase] = a32;
            out_nidx[obase] = (float)idx;
            s_ai[wslot][rank] = make_uint2(abits, (unsigned)idx);
        }

        // ---- PV (v from global: coalesced per half-wave, L2-clustered) ----
        const int d    = lane & 31;
        const int half = lane >> 5;
        float xd = 0.f;
        #pragma unroll
        for (int s16 = 0; s16 < 16; ++s16) {
            const int sI = half * 16 + s16;
            const uint2 ai = s_ai[wslot][sI];
            const float av = __uint_as_float(ai.x);
            const int   vi = (int)ai.y;
            xd += av * qkvp[(size_t)(b * N_ + vi) * C4_ + 2 * C_ + h * HD_ + d];
        }
        xd += __shfl_xor(xd, 32);
        if (half == 0) {
            const float lepe = qkvp[(size_t)(b * N_ + i) * C4_ + 3 * C_ + h * HD_ + d];
            x_pre[(size_t)(b * N_ + i) * C_ + h * HD_ + d] = xd + lepe;
        }
    }
}

// ---------------------------------------------------------------------------
// Kernel B v2: x read directly from global with BLOCK-UNIFORM addresses
// (scalarizable to s_load_dwordx4 / single broadcast transaction) instead of
// LDS staging + 384 ds_read_b128 per thread. Same accumulation expression.
// ---------------------------------------------------------------------------
#define TB_ 8
__global__ __launch_bounds__(192) void proj_kernel(
    const float* __restrict__ x_pre,
    const float* __restrict__ w,
    const float* __restrict__ bias,
    float* __restrict__ out)
{
    const int o    = threadIdx.x;            // 0..191
    const int tok0 = blockIdx.x * TB_;

    float accv[TB_];
    #pragma unroll
    for (int t = 0; t < TB_; ++t) accv[t] = 0.f;

    const float* wrow = w + (size_t)o * C_;
    const float* xbase = x_pre + (size_t)tok0 * C_;
    for (int c = 0; c < C_; c += 4) {
        const float4 wv = *(const float4*)(wrow + c);
        #pragma unroll
        for (int t = 0; t < TB_; ++t) {
            const float4 xv = *(const float4*)(xbase + t * C_ + c);  // uniform
            accv[t] += xv.x * wv.x + xv.y * wv.y + xv.z * wv.z + xv.w * wv.w;
        }
    }
    const float bo = bias[o];
    #pragma unroll
    for (int t = 0; t < TB_; ++t)
        out[(size_t)(tok0 + t) * C_ + o] = accv[t] + bo;
}

// ---------------------------------------------------------------------------
extern "C" void kernel_launch(void* const* d_in, const int* in_sizes, int n_in,
                              void* d_out, int out_size, void* d_ws, size_t ws_size,
                              hipStream_t stream) {
    const float* qkvp       = (const float*)d_in[0];
    const float* pfa_values = (const float*)d_in[1];
    const int*   pfa_index  = (const int*)d_in[2];
    const int*   rpi        = (const int*)d_in[3];
    const float* rpb_table  = (const float*)d_in[4];
    const float* proj_w     = (const float*)d_in[5];
    const float* proj_b     = (const float*)d_in[6];

    float* out = (float*)d_out;
    float* out_x    = out;
    float* out_topv = out + (size_t)B_ * N_ * C_;
    float* out_nidx = out_topv + (size_t)B_ * H_ * N_ * TKOUT;

    float* x_pre = (float*)d_ws;

    attn_topk_kernel<<<768, 512, 0, stream>>>(
        qkvp, pfa_values, pfa_index, rpi, rpb_table, x_pre, out_topv, out_nidx);

    const int ntok = B_ * N_;                            // 8192
    proj_kernel<<<ntok / TB_, 192, 0, stream>>>(x_pre, proj_w, proj_b, out_x);
}